// Round 6
// baseline (173.036 us; speedup 1.0000x reference)
//
#include <hip/hip_runtime.h>

// Problem constants (static from reference setup_inputs)
constexpr int BB = 8, CC = 4, HH = 1024, WW = 1024, CROP = 5;
constexpr int HC = HH - 2 * CROP, WC = WW - 2 * CROP;   // 1014 x 1014
constexpr int HW = HH * WW;
constexpr float AA = -0.75f;                            // PyTorch bicubic A

constexpr int PBLK = 1536;                   // 6 WGs/CU (LDS 16KB x 6 = 96KB)
constexpr int NSEG = BB * HC * 4;            // 32448 segments (b, y, chunk)
constexpr int SW = 288;                      // staged window width (floats)
constexpr int SFL = 4096;                    // staged floats/channel (16KB)

// Cheap reflection valid for |i| <= 2046
__device__ __forceinline__ int reflect_small(int i) {
    int r = i < 0 ? -i : i;
    return r > (HH - 1) ? 2 * (HH - 1) - r : r;
}

__device__ __forceinline__ void cubic_w(float t, float& w0, float& w1,
                                        float& w2, float& w3) {
    float t1 = t + 1.0f;
    w0 = ((AA * t1 - 5.0f * AA) * t1 + 8.0f * AA) * t1 - 4.0f * AA;
    w1 = ((AA + 2.0f) * t - (AA + 3.0f)) * t * t + 1.0f;
    float s = 1.0f - t;
    w2 = ((AA + 2.0f) * s - (AA + 3.0f)) * s * s + 1.0f;
    float s2 = 2.0f - t;
    w3 = ((AA * s2 - 5.0f * AA) * s2 + 8.0f * AA) * s2 - 4.0f * AA;
}

// rare fallback: scalar reflected global taps for one pixel, all 4 channels
__device__ __noinline__ float px_slow(const float* __restrict__ tgt_b,
                                      const float* __restrict__ in_b, int pix,
                                      int bx, int by, float wx0, float wx1,
                                      float wx2, float wx3, float wy0,
                                      float wy1, float wy2, float wy3) {
    const int r0 = reflect_small(by - 1) * WW;
    const int r1 = reflect_small(by) * WW;
    const int r2 = reflect_small(by + 1) * WW;
    const int r3 = reflect_small(by + 2) * WW;
    const int c0 = reflect_small(bx - 1);
    const int c1 = reflect_small(bx);
    const int c2 = reflect_small(bx + 1);
    const int c3 = reflect_small(bx + 2);
    float acc = 0.0f;
#pragma unroll
    for (int c = 0; c < CC; ++c) {
        const float* tb = tgt_b + c * HW;
        float q0 = wx0 * tb[r0 + c0] + wx1 * tb[r0 + c1] + wx2 * tb[r0 + c2] +
                   wx3 * tb[r0 + c3];
        float q1 = wx0 * tb[r1 + c0] + wx1 * tb[r1 + c1] + wx2 * tb[r1 + c2] +
                   wx3 * tb[r1 + c3];
        float q2 = wx0 * tb[r2 + c0] + wx1 * tb[r2 + c1] + wx2 * tb[r2 + c2] +
                   wx3 * tb[r2 + c3];
        float q3 = wx0 * tb[r3 + c0] + wx1 * tb[r3 + c1] + wx2 * tb[r3 + c2] +
                   wx3 * tb[r3 + c3];
        float v = wy0 * q0 + wy1 * q1 + wy2 * q2 + wy3 * q3;
        acc += fabsf(in_b[c * HW + pix] - v);
    }
    return acc;
}

typedef __attribute__((address_space(1))) const void gv_t;
typedef __attribute__((address_space(3))) void lv_t;

__global__ __launch_bounds__(256, 6) void warp_loss_k(
    const float* __restrict__ input, const float* __restrict__ target,
    const float* __restrict__ flow, float* __restrict__ wsbuf) {
    __shared__ float cache[SFL];
    const int tid = (int)threadIdx.x;
    const int wv = tid >> 6, lane = tid & 63;

    // segment-invariant staging geometry: instr k of wave wv covers floats
    // F = (wv*4+k)*256 + lane*4 of the flat [15r x 288c] window.
    int rS[4], cS[4];
#pragma unroll
    for (int k = 0; k < 4; ++k) {
        int F = (wv * 4 + k) * 256 + lane * 4;
        rS[k] = F / SW;
        cS[k] = F % SW;
    }

    float lsum = 0.0f;

    for (int seg = blockIdx.x; seg < NSEG; seg += PBLK) {
        const int chunk = seg & 3;
        const int row = seg >> 2;
        const int y = row % HC + CROP;
        const int b = row / HC;
        const int x0 = CROP + chunk * 256;
        const int x = x0 + tid;
        const bool valid = x < CROP + WC;
        const int wscol = x0 - 9;  // window start col (== 0 mod 4 -> 16B ok)

        const float* tgt_b = target + (size_t)b * CC * HW;
        const float* in_b = input + (size_t)b * CC * HW;
        const float* flow_b = flow + (size_t)b * 2 * HW;
        const int pix = y * WW + x;  // stays in-plane even for tail threads

        const float dx = valid ? flow_b[pix] : 0.0f;
        const float dy = valid ? flow_b[HW + pix] : 0.0f;
        float i0 = 0, i1 = 0, i2 = 0, i3 = 0;
        if (valid) {
            i0 = in_b[pix];
            i1 = in_b[HW + pix];
            i2 = in_b[2 * HW + pix];
            i3 = in_b[3 * HW + pix];
        }

        const float ix = (float)x + dx;
        const float iy = (float)y + dy;
        const float bxf = floorf(ix), byf = floorf(iy);
        const float tx = ix - bxf, ty = iy - byf;
        const int bx = (int)bxf, by = (int)byf;

        float wx0, wx1, wx2, wx3, wy0, wy1, wy2, wy3;
        cubic_w(tx, wx0, wx1, wx2, wx3);
        cubic_w(ty, wy0, wy1, wy2, wy3);

        // tap start in LDS coords: rows staged are y-6 .. y+8 (r=0..14)
        const int c0 = bx - x0 + 8;
        const int r0 = by - y + 5;
        const bool fast = valid && ((unsigned)c0 <= 284u) && ((unsigned)r0 <= 10u);
        const bool slow = valid && !fast;

        // per-segment staging source offsets (channel-independent)
        int off[4];
#pragma unroll
        for (int k = 0; k < 4; ++k) {
            int rowg = reflect_small(y - 6 + rS[k]);
            int colg = wscol + cS[k];
            colg = min(max(colg, 0), WW - 4);
            off[k] = rowg * WW + colg;
        }

#pragma unroll
        for (int ch = 0; ch < CC; ++ch) {
            __syncthreads();  // previous buffer fully consumed
            const float* plane = tgt_b + ch * HW;
#pragma unroll
            for (int k = 0; k < 4; ++k) {
                __builtin_amdgcn_global_load_lds(
                    (gv_t*)(plane + off[k]),
                    (lv_t*)&cache[(wv * 4 + k) * 256], 16, 0, 0);
            }
            __syncthreads();  // drains vmcnt(0) -> staging visible

            // edge-column fixup: bake x-reflection into the staged window
            if (chunk == 0) {
                if (tid < 56) {  // cols 0..3 hold colg -4..-1 -> reflect 4-c
                    int r = tid >> 2, c = tid & 3;
                    cache[r * SW + c] =
                        plane[reflect_small(y - 6 + r) * WW + (4 - c)];
                }
                __syncthreads();
            } else if (chunk == 3) {
                if (tid < 392) {  // cols 260..287 hold colg 1024..1051
                    int r = tid / 28, c = 260 + tid % 28;
                    cache[r * SW + c] =
                        plane[reflect_small(y - 6 + r) * WW + (1282 - c)];
                }
                __syncthreads();
            }

            if (fast) {
                const int l0 = r0 * SW + c0;
                float v = 0.0f;
#pragma unroll
                for (int j = 0; j < 4; ++j) {
                    const int base = l0 + j * SW;
                    float t0 = cache[base];
                    float t1 = cache[base + 1];
                    float t2 = cache[base + 2];
                    float t3 = cache[base + 3];
                    float q = t0 * wx0 + t1 * wx1 + t2 * wx2 + t3 * wx3;
                    float wyj = (j == 0) ? wy0 : (j == 1) ? wy1
                                : (j == 2) ? wy2 : wy3;
                    v += wyj * q;
                }
                const float ivc = (ch == 0) ? i0 : (ch == 1) ? i1
                                  : (ch == 2) ? i2 : i3;
                lsum += fabsf(ivc - v);
            }
        }

        if (slow) {
            lsum += px_slow(tgt_b, in_b, pix, bx, by, wx0, wx1, wx2, wx3,
                            wy0, wy1, wy2, wy3);
        }
    }

    // wave-64 shuffle reduction + per-block partial (no global atomic)
#pragma unroll
    for (int off2 = 32; off2 > 0; off2 >>= 1) lsum += __shfl_down(lsum, off2);

    __shared__ float sm[4];
    if (lane == 0) sm[wv] = lsum;
    __syncthreads();
    if (tid == 0) wsbuf[blockIdx.x] = sm[0] + sm[1] + sm[2] + sm[3];
}

__global__ __launch_bounds__(1024) void reduce_k(const float* __restrict__ ws,
                                                 float* __restrict__ out) {
    float s = 0.0f;
    for (int i = threadIdx.x; i < PBLK; i += 1024) s += ws[i];
#pragma unroll
    for (int off = 32; off > 0; off >>= 1) s += __shfl_down(s, off);
    __shared__ float sm[16];
    const int lane = threadIdx.x & 63;
    const int wv = threadIdx.x >> 6;
    if (lane == 0) sm[wv] = s;
    __syncthreads();
    if (threadIdx.x == 0) {
        float t = 0.0f;
#pragma unroll
        for (int i = 0; i < 16; ++i) t += sm[i];
        constexpr float inv_count = 1.0f / ((float)BB * CC * HC * WC);
        out[0] = t * inv_count;
    }
}

extern "C" void kernel_launch(void* const* d_in, const int* in_sizes, int n_in,
                              void* d_out, int out_size, void* d_ws,
                              size_t ws_size, hipStream_t stream) {
    const float* input = (const float*)d_in[0];
    const float* target = (const float*)d_in[1];
    const float* flow = (const float*)d_in[2];
    float* ws = (float*)d_ws;
    float* out = (float*)d_out;

    warp_loss_k<<<PBLK, 256, 0, stream>>>(input, target, flow, ws);
    reduce_k<<<1, 1024, 0, stream>>>(ws, out);
}